// Round 18
// baseline (100.127 us; speedup 1.0000x reference)
//
#include <hip/hip_runtime.h>
#include <hip/hip_bf16.h>
#include <math.h>

#define B_ 2
#define T_ 2048
#define C_ 1024
#define H_ 16
// head dim = 64

typedef __bf16 bf16x8 __attribute__((ext_vector_type(8)));
typedef __bf16 bf16x4 __attribute__((ext_vector_type(4)));
typedef float f32x4 __attribute__((ext_vector_type(4)));
typedef float f32x16 __attribute__((ext_vector_type(16)));
typedef unsigned int u32;

#if __has_builtin(__builtin_amdgcn_exp2f)
#define EXP2(x) __builtin_amdgcn_exp2f(x)
#else
#define EXP2(x) exp2f(x)
#endif

__device__ __forceinline__ void gload16(const void* g, void* l) {
    __builtin_amdgcn_global_load_lds(
        (const __attribute__((address_space(1))) void*)g,
        (__attribute__((address_space(3))) void*)l, 16, 0, 0);
}

__device__ __forceinline__ f32x4 mfma16(bf16x8 a, bf16x8 b, f32x4 c) {
    return __builtin_amdgcn_mfma_f32_16x16x32_bf16(a, b, c, 0, 0, 0);
}
__device__ __forceinline__ f32x16 mfma32(bf16x8 a, bf16x8 b, f32x16 c) {
    return __builtin_amdgcn_mfma_f32_32x32x16_bf16(a, b, c, 0, 0, 0);
}

__device__ __forceinline__ u32 cvtpk(float lo, float hi) {
    u32 r;
    asm("v_cvt_pk_bf16_f32 %0, %1, %2" : "=v"(r) : "v"(lo), "v"(hi));
    return r;
}

__device__ __forceinline__ void plane32swap(u32& a, u32& b) {
#if __has_builtin(__builtin_amdgcn_permlane32_swap)
    auto r = __builtin_amdgcn_permlane32_swap(a, b, false, false);
    a = r[0]; b = r[1];
#else
    asm("v_permlane32_swap_b32 %0, %1" : "+v"(a), "+v"(b));
#endif
}

#define SCLQ 0.18033688011112042f   /* 0.125 * log2(e) */
#define NLOG2_10K_32 (-0.4152410118609203f)  /* -log2(10000)/32 */

// ---------------- fused fp32 -> bf16 casts (x, w_attn, w_proj) ----------------
__global__ __launch_bounds__(256) void cast_all(const float* __restrict__ x,
                                                const float* __restrict__ wa,
                                                const float* __restrict__ wp,
                                                __bf16* __restrict__ xb,
                                                __bf16* __restrict__ wab,
                                                __bf16* __restrict__ wpb) {
    const int i = blockIdx.x * 256 + threadIdx.x;   // float4 units
    const float* src;
    __bf16* dst;
    int k;
    if (i < 1048576)               { src = x;  dst = xb;  k = i; }
    else if (i < 1048576 + 786432) { src = wa; dst = wab; k = i - 1048576; }
    else                           { src = wp; dst = wpb; k = i - (1048576 + 786432); }
    float4 v = ((const float4*)src)[k];
    bf16x4 o;
    o[0] = (__bf16)v.x; o[1] = (__bf16)v.y; o[2] = (__bf16)v.z; o[3] = (__bf16)v.w;
    ((bf16x4*)dst)[k] = o;
}

// ---------------- qkv GEMM (128x128) + XOR-swizzled LDS + RoPE epilogue -------
__global__ __launch_bounds__(256) void gemm_qkv(const __bf16* __restrict__ A,
                                                const __bf16* __restrict__ Bw,
                                                __bf16* __restrict__ Qb,
                                                __bf16* __restrict__ Kb,
                                                __bf16* __restrict__ Vt) {
    const int tid  = threadIdx.x;
    const int lane = tid & 63;
    const int w    = tid >> 6;
    const int wr = w >> 1, wc = w & 1;
    const int l15 = lane & 15, lg = lane >> 4;
    // bijective XCD-grouped remap of the 24x32 grid (dispatch id: x fastest)
    const int d0  = blockIdx.y * 24 + blockIdx.x;  // 0..767
    const int xcd = d0 & 7, kk0 = d0 >> 3;         // kk0: 0..95
    const int by  = xcd * 4 + (kk0 / 24);          // 0..31
    const int bx  = kk0 % 24;                      // 0..23
    const int bm = by * 128, bn = bx * 128;
    const int K = C_;
    __shared__ __bf16 Asm[128 * 64];
    __shared__ __bf16 Bsm[128 * 64];
    f32x4 acc[4][4] = {};

    for (int kt = 0; kt < K; kt += 64) {
        if (kt) __syncthreads();
#pragma unroll
        for (int it = 0; it < 4; ++it) {
            const int c = it * 256 + tid;
            const int row = c >> 3, sg = (c & 7) ^ (row & 7);
            gload16(A  + (size_t)(bm + row) * K + kt + sg * 8, Asm + c * 8);
            gload16(Bw + (size_t)(bn + row) * K + kt + sg * 8, Bsm + c * 8);
        }
        __syncthreads();
#pragma unroll
        for (int k2 = 0; k2 < 2; ++k2) {
            bf16x8 af[4], bf[4];
#pragma unroll
            for (int i = 0; i < 4; ++i) {
                const int row = wr * 64 + i * 16 + l15;
                af[i] = *(const bf16x8*)&Asm[row * 64 + (((k2 * 4 + lg) ^ (row & 7)) * 8)];
            }
#pragma unroll
            for (int j = 0; j < 4; ++j) {
                const int row = wc * 64 + j * 16 + l15;
                bf[j] = *(const bf16x8*)&Bsm[row * 64 + (((k2 * 4 + lg) ^ (row & 7)) * 8)];
            }
#pragma unroll
            for (int i = 0; i < 4; ++i)
#pragma unroll
                for (int j = 0; j < 4; ++j)
                    acc[i][j] = mfma16(af[i], bf[j], acc[i][j]);
        }
    }
    // ---- fused epilogue: RoPE q/k in-register, scatter Q/K/V^T ----
    const int region  = bn >> 10;                 // 0=q, 1=k, 2=v
    const int colbase = (bn & 1023) + wc * 64;    // 64-aligned
    const int h = colbase >> 6;
    if (region < 2) {
        __bf16* dst = region ? Kb : Qb;
        const float scl = region ? 1.0f : SCLQ;
#pragma unroll
        for (int j = 0; j < 2; ++j) {
            const int d = j * 16 + l15;           // 0..31; partner d+32 at j+2
            const float invf = exp2f((float)d * NLOG2_10K_32);
#pragma unroll
            for (int i = 0; i < 4; ++i)
#pragma unroll
                for (int r = 0; r < 4; ++r) {
                    const int row = bm + wr * 64 + i * 16 + lg * 4 + r;
                    const int b = row >> 11, t = row & (T_ - 1);
                    float sv, cv;
                    __sincosf((float)t * invf, &sv, &cv);
                    const float v1 = acc[i][j][r], v2 = acc[i][j + 2][r];
                    const float o1 = (v1 * cv - v2 * sv) * scl;
                    const float o2 = (v2 * cv + v1 * sv) * scl;
                    const size_t base = ((size_t)(b * H_ + h) * T_ + t) * 64;
                    dst[base + d]      = (__bf16)o1;
                    dst[base + d + 32] = (__bf16)o2;
                }
        }
    } else {
#pragma unroll
        for (int i = 0; i < 4; ++i)
#pragma unroll
            for (int j = 0; j < 4; ++j) {
                const int vcol = colbase + j * 16 + l15;
                const int hh = vcol >> 6, d = vcol & 63;
                const int row0 = bm + wr * 64 + i * 16 + lg * 4;
                const int b = row0 >> 11, t0 = row0 & (T_ - 1);
                u32 dw[2];
                dw[0] = cvtpk(acc[i][j][0], acc[i][j][1]);
                dw[1] = cvtpk(acc[i][j][2], acc[i][j][3]);
                *(uint64_t*)&Vt[((size_t)(b * H_ + hh) * 64 + d) * T_ + t0] =
                    *(uint64_t*)dw;
            }
    }
}

// ---------------- proj GEMM: BM=64, XCD remap, XOR-swizzled LDS ----------------
__global__ __launch_bounds__(256) void gemm_proj(const __bf16* __restrict__ A,
                                                 const __bf16* __restrict__ Bw,
                                                 float* __restrict__ Cp,
                                                 int N, int K) {
    const int tid  = threadIdx.x;
    const int lane = tid & 63;
    const int w    = tid >> 6;
    const int wr = w >> 1, wc = w & 1;
    const int l15 = lane & 15, lg = lane >> 4;
    const int d0  = blockIdx.y * 8 + blockIdx.x;   // 0..511
    const int xcd = d0 & 7, kk0 = d0 >> 3;         // kk0: 0..63
    const int by  = xcd * 8 + (kk0 >> 3);          // 0..63
    const int bx  = kk0 & 7;                       // 0..7
    const int bm = by * 64, bn = bx * 128;
    __shared__ __bf16 Asm[64 * 64];
    __shared__ __bf16 Bsm[128 * 64];
    f32x4 acc[2][4] = {};

    for (int kt = 0; kt < K; kt += 64) {
        if (kt) __syncthreads();
#pragma unroll
        for (int it = 0; it < 2; ++it) {
            const int g = it * 256 + tid;
            const int row = g >> 3, sg = (g & 7) ^ (row & 7);
            gload16(A + (size_t)(bm + row) * K + kt + sg * 8, Asm + g * 8);
        }
#pragma unroll
        for (int it = 0; it < 4; ++it) {
            const int g = it * 256 + tid;
            const int row = g >> 3, sg = (g & 7) ^ (row & 7);
            gload16(Bw + (size_t)(bn + row) * K + kt + sg * 8, Bsm + g * 8);
        }
        __syncthreads();
#pragma unroll
        for (int k2 = 0; k2 < 2; ++k2) {
            bf16x8 af[2], bf[4];
#pragma unroll
            for (int i = 0; i < 2; ++i) {
                const int row = wr * 32 + i * 16 + l15;
                af[i] = *(const bf16x8*)&Asm[row * 64 + (((k2 * 4 + lg) ^ (row & 7)) * 8)];
            }
#pragma unroll
            for (int j = 0; j < 4; ++j) {
                const int row = wc * 64 + j * 16 + l15;
                bf[j] = *(const bf16x8*)&Bsm[row * 64 + (((k2 * 4 + lg) ^ (row & 7)) * 8)];
            }
#pragma unroll
            for (int i = 0; i < 2; ++i)
#pragma unroll
                for (int j = 0; j < 4; ++j)
                    acc[i][j] = mfma16(af[i], bf[j], acc[i][j]);
        }
    }
#pragma unroll
    for (int i = 0; i < 2; ++i)
#pragma unroll
        for (int j = 0; j < 4; ++j)
#pragma unroll
            for (int r = 0; r < 4; ++r) {
                const int row = bm + wr * 32 + i * 16 + lg * 4 + r;
                const int col = bn + wc * 64 + j * 16 + l15;
                Cp[(size_t)row * N + col] = acc[i][j][r];
            }
}

// ---------------- causal flash attention: 4 blocks/CU, QBLK=64, KVBLK=128 -----
// R13 inner pipeline retiled for 4 INDEPENDENT barrier-groups per CU (was 2):
// 256 thr (4 waves: qgrp=w&1 x kvh=w>>1), 32KB LDS/block, grid 1024 = 4/CU.
// Mechanism (measured R4/R5): stage drains are covered by co-resident blocks'
// compute -- 4 blocks at different loop phases quadruple the coverage pool.
// Finer causal balance: 32 qt levels, CU pairs qt <-> 31-qt.
__global__ __launch_bounds__(256, 4) void attn_fwd(const __bf16* __restrict__ Qb,
                                                   const __bf16* __restrict__ Kb,
                                                   const __bf16* __restrict__ Vt,
                                                   __bf16* __restrict__ Yatt) {
    const int gid = blockIdx.x;
    const int bh = (gid & 7) * 4 + ((gid >> 3) & 3);   // same-bh blocks -> same XCD
    const int qq = gid >> 5;                           // 0..31
    const int qt = (qq < 16) ? (31 - qq) : (qq - 16);  // pair sums constant
    const int b = bh >> 4, h = bh & 15;
    const int tid = threadIdx.x, lane = tid & 63, w = tid >> 6;
    const int qgrp = w & 1, kvh = w >> 1;
    const int l31 = lane & 31, hi = lane >> 5;
    const int hi4 = hi * 4;
    __shared__ __bf16 Ksm[128 * 64];   // [kv][d], granule ^= (kv&7)       16KB
    __shared__ __bf16 Vsm[64 * 128];   // [d][kv], low-3 granule ^= (d&7)  16KB

    const int Q0 = qt * 64 + qgrp * 32;
    const int qg = Q0 + l31;
    const __bf16* Qp = Qb + ((size_t)bh * T_ + Q0) * 64;
    const __bf16* Kp = Kb + (size_t)bh * T_ * 64;
    const __bf16* Vp = Vt + (size_t)bh * 64 * T_;

    auto STAGE = [&](int jt) {
#pragma unroll
        for (int it = 0; it < 4; ++it) {           // 8 loads per thread total
            const int g = it * 256 + tid;          // granule id 0..1023 (16B)
            const int kr = g >> 3, kc = (g & 7) ^ (kr & 7);
            gload16(Kp + ((size_t)(jt * 128 + kr)) * 64 + kc * 8, Ksm + g * 8);
            const int vd = g >> 3, vg = ((g & 7) ^ (vd & 7)) | (g & 8);
            gload16(Vp + (size_t)(vd & 63) * T_ + jt * 128 +
                    ((g & 8) ? 64 : 0) + (((g & 7) ^ (vd & 7)) * 8) -
                    ((g & 8) ? 64 : 0) + ((g & 8) ? 64 : 0), Vsm + g * 8);
            (void)vg;
        }
    };
    // NOTE: lambda above simplified below -- use clean version.

    bf16x8 qf[4];
#pragma unroll
    for (int ds = 0; ds < 4; ++ds)
        qf[ds] = *(const bf16x8*)&Qp[l31 * 64 + ds * 16 + hi * 8];

    f32x16 ot[2] = {};            // O^T: d = db*32 + crow(r,hi), q = l31
    float l_run = 0.f;            // lane-local partial

    const int jmax = (qt >> 1) + 1;                // 128-wide KV tiles
    for (int jt = 0; jt < jmax; ++jt) {
        __builtin_amdgcn_s_barrier();              // prev tile reads complete
#pragma unroll
        for (int it = 0; it < 4; ++it) {           // stage K 16KB + V 16KB
            const int g = it * 256 + tid;          // granule id 0..1023
            const int kr = g >> 3, kc = (g & 7) ^ (kr & 7);
            gload16(Kp + ((size_t)(jt * 128 + kr)) * 64 + kc * 8, Ksm + g * 8);
            // V: row d = g>>4 (0..63), 16 granules/row; swizzle low-3 within
            // each 8-granule (64-kv) half: vg = ((g&7)^(d&7)) | (g&8)
            const int vd = g >> 4;
            const int vg = ((g & 7) ^ (vd & 7)) | (g & 8);
            gload16(Vp + (size_t)vd * T_ + jt * 128 + vg * 8, Vsm + g * 8);
        }
        asm volatile("s_waitcnt vmcnt(0)" ::: "memory");
        __builtin_amdgcn_s_barrier();              // tile resident (collective)
        __builtin_amdgcn_sched_barrier(0);

        if (jt * 128 + kvh * 64 <= Q0 + 31) {      // wave-uniform skip
            const bool diag = (jt == jmax - 1);
#pragma unroll
            for (int a = 0; a < 2; ++a) {          // 32-kv chunk, fused pipeline
                // ---- S^T chunk = K @ Q^T ----
                f32x16 st = {};
#pragma unroll
                for (int ds = 0; ds < 4; ++ds) {
                    const int row = kvh * 64 + a * 32 + l31;
                    const int off = (ds * 32 + hi * 16) ^ ((row & 7) << 4);
                    bf16x8 kf = *(const bf16x8*)((const char*)Ksm + row * 128 + off);
                    st = mfma32(kf, qf[ds], st);
                }
                // ---- causal mask (last tile only) ----
                if (diag) {
#pragma unroll
                    for (int r = 0; r < 16; ++r) {
                        const int kv = jt * 128 + kvh * 64 + a * 32 +
                                       (r & 3) + 8 * (r >> 2) + hi4;
                        if (kv > qg) st[r] = -1e30f;
                    }
                }
                // ---- p = exp2(s); lane-local partial sum ----
                float s0 = 0.f, s1 = 0.f;
#pragma unroll
                for (int r = 0; r < 16; ++r) {
                    const float e = EXP2(st[r]);
                    st[r] = e;
                    if (r & 1) s1 += e; else s0 += e;
                }
                l_run += s0 + s1;
                // ---- P^T chunk -> 2 B-operand frags ----
                u32 X0 = cvtpk(st[0], st[1]),  X1 = cvtpk(st[2], st[3]);
                u32 Y0 = cvtpk(st[4], st[5]),  Y1 = cvtpk(st[6], st[7]);
                plane32swap(X0, Y0); plane32swap(X1, Y1);
                u32 dw0[4] = {X0, X1, Y0, Y1};
                bf16x8 pa0 = *(bf16x8*)dw0;
                u32 Z0 = cvtpk(st[8], st[9]),   Z1 = cvtpk(st[10], st[11]);
                u32 W0 = cvtpk(st[12], st[13]), W1 = cvtpk(st[14], st[15]);
                plane32swap(Z0, W0); plane32swap(Z1, W1);
                u32 dw1[4] = {Z0, Z1, W0, W1};
                bf16x8 pa1 = *(bf16x8*)dw1;
                // ---- O^T += V^T-as-A @ P^T-as-B ----
                // source granules (16/row): s0 = kvh*8 + 4a + hi, s1 = s0 + 2;
                // read LDS granule = (s&8) | ((s&7) ^ (d&7))
#pragma unroll
                for (int db = 0; db < 2; ++db) {
                    const int row = db * 32 + l31;
                    const int s0g = kvh * 8 + 4 * a + hi;
                    const int s1g = s0g + 2;
                    const int g0 = (s0g & 8) | ((s0g & 7) ^ (row & 7));
                    const int g1 = (s1g & 8) | ((s1g & 7) ^ (row & 7));
                    bf16x8 v0 = *(const bf16x8*)((const char*)Vsm + row * 256 + g0 * 16);
                    bf16x8 v1 = *(const bf16x8*)((const char*)Vsm + row * 256 + g1 * 16);
                    ot[db] = mfma32(v0, pa0, ot[db]);
                    ot[db] = mfma32(v1, pa1, ot[db]);
                }
            }
        }
    }
    // ---- merge kv-half partials (waves 2,3 -> waves 0,1) via LDS ----
    __builtin_amdgcn_s_barrier();              // all tile reads complete
    f32x4* m4 = (f32x4*)&Ksm[0];               // 8 x 128 x f32x4 = 16KB
    float* lb = (float*)&Vsm[0];               // 128 f32 (lane-local partials)
    if (w >= 2) {
        const int woff = (w - 2) * 64 + lane;
#pragma unroll
        for (int db = 0; db < 2; ++db)
#pragma unroll
            for (int rq = 0; rq < 4; ++rq) {
                f32x4 v;
                v[0] = ot[db][rq * 4 + 0]; v[1] = ot[db][rq * 4 + 1];
                v[2] = ot[db][rq * 4 + 2]; v[3] = ot[db][rq * 4 + 3];
                m4[(db * 4 + rq) * 128 + woff] = v;
            }
        lb[woff] = l_run;
    }
    __builtin_amdgcn_s_barrier();
    if (w < 2) {
        const int woff = w * 64 + lane;
#pragma unroll
        for (int db = 0; db < 2; ++db)
#pragma unroll
            for (int rq = 0; rq < 4; ++rq) {
                f32x4 v = m4[(db * 4 + rq) * 128 + woff];
                ot[db][rq * 4 + 0] += v[0]; ot[db][rq * 4 + 1] += v[1];
                ot[db][rq * 4 + 2] += v[2]; ot[db][rq * 4 + 3] += v[3];
            }
        l_run += lb[woff];
        l_run += __shfl_xor(l_run, 32);        // single deferred cross-half sum
        const float inv = 1.f / l_run;
        __bf16* Yp = Yatt + ((size_t)(b * T_ + qg)) * C_ + h * 64;
#pragma unroll
        for (int db = 0; db < 2; ++db)
#pragma unroll
            for (int rq = 0; rq < 4; ++rq) {
                const int r = rq * 4;
                u32 dw[2];
                dw[0] = cvtpk(ot[db][r] * inv,     ot[db][r + 1] * inv);
                dw[1] = cvtpk(ot[db][r + 2] * inv, ot[db][r + 3] * inv);
                const int d = db * 32 + 8 * rq + hi4;
                *(uint64_t*)&Yp[d] = *(uint64_t*)dw;
            }
    }
}

extern "C" void kernel_launch(void* const* d_in, const int* in_sizes, int n_in,
                              void* d_out, int out_size, void* d_ws, size_t ws_size,
                              hipStream_t stream) {
    const float* x      = (const float*)d_in[0];
    const float* w_attn = (const float*)d_in[1];
    const float* w_proj = (const float*)d_in[2];
    float* out = (float*)d_out;
    char* ws = (char*)d_ws;

    __bf16* xb  = (__bf16*)(ws);               //  8.39 MB
    __bf16* wab = (__bf16*)(ws + 8388608);     //  6.29 MB
    __bf16* wpb = (__bf16*)(ws + 14680064);    //  2.10 MB
    __bf16* Qb  = (__bf16*)(ws + 16777216);    //  8.39 MB [B,H,T,64] roped+scaled
    __bf16* Kb  = (__bf16*)(ws + 25165824);    //  8.39 MB [B,H,T,64] roped
    __bf16* Vt  = (__bf16*)(ws + 33554432);    //  8.39 MB [B,H,64,T]
    __bf16* Ya  = (__bf16*)(ws + 41943040);    //  8.39 MB attn out [4096,1024]

    cast_all<<<dim3(8192), 256, 0, stream>>>(x, w_attn, w_proj, xb, wab, wpb);

    gemm_qkv<<<dim3(3 * C_ / 128, B_ * T_ / 128), 256, 0, stream>>>(
        xb, wab, Qb, Kb, Vt);

    attn_fwd<<<dim3(32 * 32), 256, 0, stream>>>(Qb, Kb, Vt, Ya);

    gemm_proj<<<dim3(C_ / 128, B_ * T_ / 64), 256, 0, stream>>>(
        Ya, wpb, out, C_, C_);
}

// Round 19
// 89.009 us; speedup vs baseline: 1.1249x; 1.1249x over previous
//
#include <hip/hip_runtime.h>
#include <hip/hip_bf16.h>
#include <math.h>

#define B_ 2
#define T_ 2048
#define C_ 1024
#define H_ 16
// head dim = 64

typedef __bf16 bf16x8 __attribute__((ext_vector_type(8)));
typedef __bf16 bf16x4 __attribute__((ext_vector_type(4)));
typedef float f32x4 __attribute__((ext_vector_type(4)));
typedef float f32x16 __attribute__((ext_vector_type(16)));
typedef unsigned int u32;

#if __has_builtin(__builtin_amdgcn_exp2f)
#define EXP2(x) __builtin_amdgcn_exp2f(x)
#else
#define EXP2(x) exp2f(x)
#endif

__device__ __forceinline__ void gload16(const void* g, void* l) {
    __builtin_amdgcn_global_load_lds(
        (const __attribute__((address_space(1))) void*)g,
        (__attribute__((address_space(3))) void*)l, 16, 0, 0);
}

__device__ __forceinline__ f32x4 mfma16(bf16x8 a, bf16x8 b, f32x4 c) {
    return __builtin_amdgcn_mfma_f32_16x16x32_bf16(a, b, c, 0, 0, 0);
}
__device__ __forceinline__ f32x16 mfma32(bf16x8 a, bf16x8 b, f32x16 c) {
    return __builtin_amdgcn_mfma_f32_32x32x16_bf16(a, b, c, 0, 0, 0);
}

__device__ __forceinline__ u32 cvtpk(float lo, float hi) {
    u32 r;
    asm("v_cvt_pk_bf16_f32 %0, %1, %2" : "=v"(r) : "v"(lo), "v"(hi));
    return r;
}

__device__ __forceinline__ void plane32swap(u32& a, u32& b) {
#if __has_builtin(__builtin_amdgcn_permlane32_swap)
    auto r = __builtin_amdgcn_permlane32_swap(a, b, false, false);
    a = r[0]; b = r[1];
#else
    asm("v_permlane32_swap_b32 %0, %1" : "+v"(a), "+v"(b));
#endif
}

#define SCLQ 0.18033688011112042f   /* 0.125 * log2(e) */
#define NLOG2_10K_32 (-0.4152410118609203f)  /* -log2(10000)/32 */

// ---------------- fused fp32 -> bf16 casts (x, w_attn, w_proj) ----------------
__global__ __launch_bounds__(256) void cast_all(const float* __restrict__ x,
                                                const float* __restrict__ wa,
                                                const float* __restrict__ wp,
                                                __bf16* __restrict__ xb,
                                                __bf16* __restrict__ wab,
                                                __bf16* __restrict__ wpb) {
    const int i = blockIdx.x * 256 + threadIdx.x;   // float4 units
    const float* src;
    __bf16* dst;
    int k;
    if (i < 1048576)               { src = x;  dst = xb;  k = i; }
    else if (i < 1048576 + 786432) { src = wa; dst = wab; k = i - 1048576; }
    else                           { src = wp; dst = wpb; k = i - (1048576 + 786432); }
    float4 v = ((const float4*)src)[k];
    bf16x4 o;
    o[0] = (__bf16)v.x; o[1] = (__bf16)v.y; o[2] = (__bf16)v.z; o[3] = (__bf16)v.w;
    ((bf16x4*)dst)[k] = o;
}

// ---------------- qkv GEMM (128x128) + XOR-swizzled LDS + RoPE epilogue -------
__global__ __launch_bounds__(256) void gemm_qkv(const __bf16* __restrict__ A,
                                                const __bf16* __restrict__ Bw,
                                                __bf16* __restrict__ Qb,
                                                __bf16* __restrict__ Kb,
                                                __bf16* __restrict__ Vt) {
    const int tid  = threadIdx.x;
    const int lane = tid & 63;
    const int w    = tid >> 6;
    const int wr = w >> 1, wc = w & 1;
    const int l15 = lane & 15, lg = lane >> 4;
    // bijective XCD-grouped remap of the 24x32 grid (dispatch id: x fastest)
    const int d0  = blockIdx.y * 24 + blockIdx.x;  // 0..767
    const int xcd = d0 & 7, kk0 = d0 >> 3;         // kk0: 0..95
    const int by  = xcd * 4 + (kk0 / 24);          // 0..31
    const int bx  = kk0 % 24;                      // 0..23
    const int bm = by * 128, bn = bx * 128;
    const int K = C_;
    __shared__ __bf16 Asm[128 * 64];
    __shared__ __bf16 Bsm[128 * 64];
    f32x4 acc[4][4] = {};

    for (int kt = 0; kt < K; kt += 64) {
        if (kt) __syncthreads();
#pragma unroll
        for (int it = 0; it < 4; ++it) {
            const int c = it * 256 + tid;
            const int row = c >> 3, sg = (c & 7) ^ (row & 7);
            gload16(A  + (size_t)(bm + row) * K + kt + sg * 8, Asm + c * 8);
            gload16(Bw + (size_t)(bn + row) * K + kt + sg * 8, Bsm + c * 8);
        }
        __syncthreads();
#pragma unroll
        for (int k2 = 0; k2 < 2; ++k2) {
            bf16x8 af[4], bf[4];
#pragma unroll
            for (int i = 0; i < 4; ++i) {
                const int row = wr * 64 + i * 16 + l15;
                af[i] = *(const bf16x8*)&Asm[row * 64 + (((k2 * 4 + lg) ^ (row & 7)) * 8)];
            }
#pragma unroll
            for (int j = 0; j < 4; ++j) {
                const int row = wc * 64 + j * 16 + l15;
                bf[j] = *(const bf16x8*)&Bsm[row * 64 + (((k2 * 4 + lg) ^ (row & 7)) * 8)];
            }
#pragma unroll
            for (int i = 0; i < 4; ++i)
#pragma unroll
                for (int j = 0; j < 4; ++j)
                    acc[i][j] = mfma16(af[i], bf[j], acc[i][j]);
        }
    }
    // ---- fused epilogue: RoPE q/k in-register, scatter Q/K/V^T ----
    const int region  = bn >> 10;                 // 0=q, 1=k, 2=v
    const int colbase = (bn & 1023) + wc * 64;    // 64-aligned
    const int h = colbase >> 6;
    if (region < 2) {
        __bf16* dst = region ? Kb : Qb;
        const float scl = region ? 1.0f : SCLQ;
#pragma unroll
        for (int j = 0; j < 2; ++j) {
            const int d = j * 16 + l15;           // 0..31; partner d+32 at j+2
            const float invf = exp2f((float)d * NLOG2_10K_32);
#pragma unroll
            for (int i = 0; i < 4; ++i)
#pragma unroll
                for (int r = 0; r < 4; ++r) {
                    const int row = bm + wr * 64 + i * 16 + lg * 4 + r;
                    const int b = row >> 11, t = row & (T_ - 1);
                    float sv, cv;
                    __sincosf((float)t * invf, &sv, &cv);
                    const float v1 = acc[i][j][r], v2 = acc[i][j + 2][r];
                    const float o1 = (v1 * cv - v2 * sv) * scl;
                    const float o2 = (v2 * cv + v1 * sv) * scl;
                    const size_t base = ((size_t)(b * H_ + h) * T_ + t) * 64;
                    dst[base + d]      = (__bf16)o1;
                    dst[base + d + 32] = (__bf16)o2;
                }
        }
    } else {
#pragma unroll
        for (int i = 0; i < 4; ++i)
#pragma unroll
            for (int j = 0; j < 4; ++j) {
                const int vcol = colbase + j * 16 + l15;
                const int hh = vcol >> 6, d = vcol & 63;
                const int row0 = bm + wr * 64 + i * 16 + lg * 4;
                const int b = row0 >> 11, t0 = row0 & (T_ - 1);
                u32 dw[2];
                dw[0] = cvtpk(acc[i][j][0], acc[i][j][1]);
                dw[1] = cvtpk(acc[i][j][2], acc[i][j][3]);
                *(uint64_t*)&Vt[((size_t)(b * H_ + hh) * 64 + d) * T_ + t0] =
                    *(uint64_t*)dw;
            }
    }
}

// ---------------- proj GEMM: BM=64, XCD remap, XOR-swizzled LDS ----------------
__global__ __launch_bounds__(256) void gemm_proj(const __bf16* __restrict__ A,
                                                 const __bf16* __restrict__ Bw,
                                                 float* __restrict__ Cp,
                                                 int N, int K) {
    const int tid  = threadIdx.x;
    const int lane = tid & 63;
    const int w    = tid >> 6;
    const int wr = w >> 1, wc = w & 1;
    const int l15 = lane & 15, lg = lane >> 4;
    const int d0  = blockIdx.y * 8 + blockIdx.x;   // 0..511
    const int xcd = d0 & 7, kk0 = d0 >> 3;         // kk0: 0..63
    const int by  = xcd * 8 + (kk0 >> 3);          // 0..63
    const int bx  = kk0 & 7;                       // 0..7
    const int bm = by * 64, bn = bx * 128;
    __shared__ __bf16 Asm[64 * 64];
    __shared__ __bf16 Bsm[128 * 64];
    f32x4 acc[2][4] = {};

    for (int kt = 0; kt < K; kt += 64) {
        if (kt) __syncthreads();
#pragma unroll
        for (int it = 0; it < 2; ++it) {
            const int g = it * 256 + tid;
            const int row = g >> 3, sg = (g & 7) ^ (row & 7);
            gload16(A + (size_t)(bm + row) * K + kt + sg * 8, Asm + g * 8);
        }
#pragma unroll
        for (int it = 0; it < 4; ++it) {
            const int g = it * 256 + tid;
            const int row = g >> 3, sg = (g & 7) ^ (row & 7);
            gload16(Bw + (size_t)(bn + row) * K + kt + sg * 8, Bsm + g * 8);
        }
        __syncthreads();
#pragma unroll
        for (int k2 = 0; k2 < 2; ++k2) {
            bf16x8 af[2], bf[4];
#pragma unroll
            for (int i = 0; i < 2; ++i) {
                const int row = wr * 32 + i * 16 + l15;
                af[i] = *(const bf16x8*)&Asm[row * 64 + (((k2 * 4 + lg) ^ (row & 7)) * 8)];
            }
#pragma unroll
            for (int j = 0; j < 4; ++j) {
                const int row = wc * 64 + j * 16 + l15;
                bf[j] = *(const bf16x8*)&Bsm[row * 64 + (((k2 * 4 + lg) ^ (row & 7)) * 8)];
            }
#pragma unroll
            for (int i = 0; i < 2; ++i)
#pragma unroll
                for (int j = 0; j < 4; ++j)
                    acc[i][j] = mfma16(af[i], bf[j], acc[i][j]);
        }
    }
#pragma unroll
    for (int i = 0; i < 2; ++i)
#pragma unroll
        for (int j = 0; j < 4; ++j)
#pragma unroll
            for (int r = 0; r < 4; ++r) {
                const int row = bm + wr * 32 + i * 16 + lg * 4 + r;
                const int col = bn + wc * 64 + j * 16 + l15;
                Cp[(size_t)row * N + col] = acc[i][j][r];
            }
}

// ---------------- causal flash attention: 4 blocks/CU, QBLK=64, KVBLK=128 -----
// R18 retile with the launch-bounds spill FIXED: (256,4) empirically capped
// VGPR at 64 (spill: WRITE 19.5MB). (256,2) caps at >=256; kernel needs ~100,
// so no spill, and at <=128 VGPR + 32KB LDS the HW still co-schedules 4
// blocks/CU (grid 1024 = 4/CU). 4 independent barrier-groups per CU cover
// each other's stage drains (mechanism measured R4/R5).
__global__ __launch_bounds__(256, 2) void attn_fwd(const __bf16* __restrict__ Qb,
                                                   const __bf16* __restrict__ Kb,
                                                   const __bf16* __restrict__ Vt,
                                                   __bf16* __restrict__ Yatt) {
    const int gid = blockIdx.x;
    const int bh = (gid & 7) * 4 + ((gid >> 3) & 3);   // same-bh blocks -> same XCD
    const int qq = gid >> 5;                           // 0..31
    const int qt = (qq < 16) ? (31 - qq) : (qq - 16);  // pair sums constant
    const int b = bh >> 4, h = bh & 15;
    const int tid = threadIdx.x, lane = tid & 63, w = tid >> 6;
    const int qgrp = w & 1, kvh = w >> 1;
    const int l31 = lane & 31, hi = lane >> 5;
    const int hi4 = hi * 4;
    __shared__ __bf16 Ksm[128 * 64];   // [kv][d], granule ^= (kv&7)       16KB
    __shared__ __bf16 Vsm[64 * 128];   // [d][kv], low-3 granule ^= (d&7)  16KB

    const int Q0 = qt * 64 + qgrp * 32;
    const int qg = Q0 + l31;
    const __bf16* Qp = Qb + ((size_t)bh * T_ + Q0) * 64;
    const __bf16* Kp = Kb + (size_t)bh * T_ * 64;
    const __bf16* Vp = Vt + (size_t)bh * 64 * T_;

    bf16x8 qf[4];
#pragma unroll
    for (int ds = 0; ds < 4; ++ds)
        qf[ds] = *(const bf16x8*)&Qp[l31 * 64 + ds * 16 + hi * 8];

    f32x16 ot[2] = {};            // O^T: d = db*32 + crow(r,hi), q = l31
    float l_run = 0.f;            // lane-local partial

    const int jmax = (qt >> 1) + 1;                // 128-wide KV tiles
    for (int jt = 0; jt < jmax; ++jt) {
        __builtin_amdgcn_s_barrier();              // prev tile reads complete
#pragma unroll
        for (int it = 0; it < 4; ++it) {           // stage K 16KB + V 16KB
            const int g = it * 256 + tid;          // granule id 0..1023
            const int kr = g >> 3, kc = (g & 7) ^ (kr & 7);
            gload16(Kp + ((size_t)(jt * 128 + kr)) * 64 + kc * 8, Ksm + g * 8);
            // V: row d = g>>4 (0..63), 16 granules/row; swizzle low-3 within
            // each 8-granule (64-kv) half: vg = ((g&7)^(d&7)) | (g&8)
            const int vd = g >> 4;
            const int vg = ((g & 7) ^ (vd & 7)) | (g & 8);
            gload16(Vp + (size_t)vd * T_ + jt * 128 + vg * 8, Vsm + g * 8);
        }
        asm volatile("s_waitcnt vmcnt(0)" ::: "memory");
        __builtin_amdgcn_s_barrier();              // tile resident (collective)
        __builtin_amdgcn_sched_barrier(0);

        if (jt * 128 + kvh * 64 <= Q0 + 31) {      // wave-uniform skip
            const bool diag = (jt == jmax - 1);
#pragma unroll
            for (int a = 0; a < 2; ++a) {          // 32-kv chunk, fused pipeline
                // ---- S^T chunk = K @ Q^T ----
                f32x16 st = {};
#pragma unroll
                for (int ds = 0; ds < 4; ++ds) {
                    const int row = kvh * 64 + a * 32 + l31;
                    const int off = (ds * 32 + hi * 16) ^ ((row & 7) << 4);
                    bf16x8 kf = *(const bf16x8*)((const char*)Ksm + row * 128 + off);
                    st = mfma32(kf, qf[ds], st);
                }
                // ---- causal mask (last tile only) ----
                if (diag) {
#pragma unroll
                    for (int r = 0; r < 16; ++r) {
                        const int kv = jt * 128 + kvh * 64 + a * 32 +
                                       (r & 3) + 8 * (r >> 2) + hi4;
                        if (kv > qg) st[r] = -1e30f;
                    }
                }
                // ---- p = exp2(s); lane-local partial sum ----
                float s0 = 0.f, s1 = 0.f;
#pragma unroll
                for (int r = 0; r < 16; ++r) {
                    const float e = EXP2(st[r]);
                    st[r] = e;
                    if (r & 1) s1 += e; else s0 += e;
                }
                l_run += s0 + s1;
                // ---- P^T chunk -> 2 B-operand frags ----
                u32 X0 = cvtpk(st[0], st[1]),  X1 = cvtpk(st[2], st[3]);
                u32 Y0 = cvtpk(st[4], st[5]),  Y1 = cvtpk(st[6], st[7]);
                plane32swap(X0, Y0); plane32swap(X1, Y1);
                u32 dw0[4] = {X0, X1, Y0, Y1};
                bf16x8 pa0 = *(bf16x8*)dw0;
                u32 Z0 = cvtpk(st[8], st[9]),   Z1 = cvtpk(st[10], st[11]);
                u32 W0 = cvtpk(st[12], st[13]), W1 = cvtpk(st[14], st[15]);
                plane32swap(Z0, W0); plane32swap(Z1, W1);
                u32 dw1[4] = {Z0, Z1, W0, W1};
                bf16x8 pa1 = *(bf16x8*)dw1;
                // ---- O^T += V^T-as-A @ P^T-as-B ----
                // source granules (16/row): s0 = kvh*8 + 4a + hi, s1 = s0 + 2;
                // read LDS granule = (s&8) | ((s&7) ^ (d&7))
#pragma unroll
                for (int db = 0; db < 2; ++db) {
                    const int row = db * 32 + l31;
                    const int s0g = kvh * 8 + 4 * a + hi;
                    const int s1g = s0g + 2;
                    const int g0 = (s0g & 8) | ((s0g & 7) ^ (row & 7));
                    const int g1 = (s1g & 8) | ((s1g & 7) ^ (row & 7));
                    bf16x8 v0 = *(const bf16x8*)((const char*)Vsm + row * 256 + g0 * 16);
                    bf16x8 v1 = *(const bf16x8*)((const char*)Vsm + row * 256 + g1 * 16);
                    ot[db] = mfma32(v0, pa0, ot[db]);
                    ot[db] = mfma32(v1, pa1, ot[db]);
                }
            }
        }
    }
    // ---- merge kv-half partials (waves 2,3 -> waves 0,1) via LDS ----
    __builtin_amdgcn_s_barrier();              // all tile reads complete
    f32x4* m4 = (f32x4*)&Ksm[0];               // 8 x 128 x f32x4 = 16KB
    float* lb = (float*)&Vsm[0];               // 128 f32 (lane-local partials)
    if (w >= 2) {
        const int woff = (w - 2) * 64 + lane;
#pragma unroll
        for (int db = 0; db < 2; ++db)
#pragma unroll
            for (int rq = 0; rq < 4; ++rq) {
                f32x4 v;
                v[0] = ot[db][rq * 4 + 0]; v[1] = ot[db][rq * 4 + 1];
                v[2] = ot[db][rq * 4 + 2]; v[3] = ot[db][rq * 4 + 3];
                m4[(db * 4 + rq) * 128 + woff] = v;
            }
        lb[woff] = l_run;
    }
    __builtin_amdgcn_s_barrier();
    if (w < 2) {
        const int woff = w * 64 + lane;
#pragma unroll
        for (int db = 0; db < 2; ++db)
#pragma unroll
            for (int rq = 0; rq < 4; ++rq) {
                f32x4 v = m4[(db * 4 + rq) * 128 + woff];
                ot[db][rq * 4 + 0] += v[0]; ot[db][rq * 4 + 1] += v[1];
                ot[db][rq * 4 + 2] += v[2]; ot[db][rq * 4 + 3] += v[3];
            }
        l_run += lb[woff];
        l_run += __shfl_xor(l_run, 32);        // single deferred cross-half sum
        const float inv = 1.f / l_run;
        __bf16* Yp = Yatt + ((size_t)(b * T_ + qg)) * C_ + h * 64;
#pragma unroll
        for (int db = 0; db < 2; ++db)
#pragma unroll
            for (int rq = 0; rq < 4; ++rq) {
                const int r = rq * 4;
                u32 dw[2];
                dw[0] = cvtpk(ot[db][r] * inv,     ot[db][r + 1] * inv);
                dw[1] = cvtpk(ot[db][r + 2] * inv, ot[db][r + 3] * inv);
                const int d = db * 32 + 8 * rq + hi4;
                *(uint64_t*)&Yp[d] = *(uint64_t*)dw;
            }
    }
}

extern "C" void kernel_launch(void* const* d_in, const int* in_sizes, int n_in,
                              void* d_out, int out_size, void* d_ws, size_t ws_size,
                              hipStream_t stream) {
    const float* x      = (const float*)d_in[0];
    const float* w_attn = (const float*)d_in[1];
    const float* w_proj = (const float*)d_in[2];
    float* out = (float*)d_out;
    char* ws = (char*)d_ws;

    __bf16* xb  = (__bf16*)(ws);               //  8.39 MB
    __bf16* wab = (__bf16*)(ws + 8388608);     //  6.29 MB
    __bf16* wpb = (__bf16*)(ws + 14680064);    //  2.10 MB
    __bf16* Qb  = (__bf16*)(ws + 16777216);    //  8.39 MB [B,H,T,64] roped+scaled
    __bf16* Kb  = (__bf16*)(ws + 25165824);    //  8.39 MB [B,H,T,64] roped
    __bf16* Vt  = (__bf16*)(ws + 33554432);    //  8.39 MB [B,H,64,T]
    __bf16* Ya  = (__bf16*)(ws + 41943040);    //  8.39 MB attn out [4096,1024]

    cast_all<<<dim3(8192), 256, 0, stream>>>(x, w_attn, w_proj, xb, wab, wpb);

    gemm_qkv<<<dim3(3 * C_ / 128, B_ * T_ / 128), 256, 0, stream>>>(
        xb, wab, Qb, Kb, Vt);

    attn_fwd<<<dim3(32 * 32), 256, 0, stream>>>(Qb, Kb, Vt, Ya);

    gemm_proj<<<dim3(C_ / 128, B_ * T_ / 64), 256, 0, stream>>>(
        Ya, wpb, out, C_, C_);
}